// Round 7
// baseline (3097.928 us; speedup 1.0000x reference)
//
#include <hip/hip_runtime.h>
#include <hip/hip_bf16.h>

// Sizes (fixed for this problem)
#define BATCH 2
#define LSEQ 512
#define DMODEL 1024
#define DINNER 2048
#define DSTATE 16
#define DTRANK 64
#define DCONV 4
#define EVENTD 10
#define TIMED 6
#define BT (BATCH*LSEQ)   // 1024
#define NCH 32            // scan chunks
#define CL  16            // steps per chunk (NCH*CL == LSEQ)

typedef unsigned int u32;
typedef unsigned short u16;
typedef unsigned long long u64;
typedef __attribute__((ext_vector_type(8))) short short8;
typedef __attribute__((ext_vector_type(4))) float f32x4;
typedef _Float16 h2_t __attribute__((ext_vector_type(2)));

__device__ __forceinline__ float sigmoidf_(float x) { return 1.f/(1.f+__expf(-x)); }
__device__ __forceinline__ u16 to_bf16_(float f) {
    u32 u = __float_as_uint(f);
    return (u16)((u + 0x7FFFu + ((u >> 16) & 1u)) >> 16);
}
__device__ __forceinline__ u32 pack_h2(float a, float b) {
    _Float16 ha = (_Float16)a, hb = (_Float16)b;
    u16 ua, ub;
    __builtin_memcpy(&ua, &ha, 2);
    __builtin_memcpy(&ub, &hb, 2);
    return (u32)ua | ((u32)ub << 16);
}
__device__ __forceinline__ u16 to_h16_(float a) {
    _Float16 ha = (_Float16)a;
    u16 ua; __builtin_memcpy(&ua, &ha, 2);
    return ua;
}

// ---------------------------------------------------------------------------
// Fused weight/activation conversion (pair-granular, one kernel).
// whh -> fp16 pairs; ipw/wih/opw/x -> bf16 pairs.
// ---------------------------------------------------------------------------
__global__ void convert_all(const float* __restrict__ whh, u32* __restrict__ whh_h2,
                            const float* __restrict__ ipw, u32* __restrict__ ipw_bf,
                            const float* __restrict__ wih, u32* __restrict__ wih_bf,
                            const float* __restrict__ opw, u32* __restrict__ opw_bf,
                            const float* __restrict__ xx,  u32* __restrict__ x_bf) {
    const int n0 = 3*DINNER*DINNER/2;        // 6,291,456 pairs (fp16)
    const int n1 = 2*DINNER*DMODEL/2;        // 4,194,304
    const int n2 = 3*DINNER*DINNER/2;        // 6,291,456
    const int n3 = DMODEL*DINNER/2;          // 1,048,576
    const int n4 = BT*DMODEL/2;              //   524,288
    int total = n0+n1+n2+n3+n4;
    for (int i = blockIdx.x*blockDim.x + threadIdx.x; i < total; i += gridDim.x*blockDim.x) {
        const float2* s; u32* d; int k; bool h2m = false;
        if (i < n0)              { s = (const float2*)whh; d = whh_h2; k = i; h2m = true; }
        else if (i < n0+n1)      { s = (const float2*)ipw; d = ipw_bf; k = i-n0; }
        else if (i < n0+n1+n2)   { s = (const float2*)wih; d = wih_bf; k = i-n0-n1; }
        else if (i < n0+n1+n2+n3){ s = (const float2*)opw; d = opw_bf; k = i-n0-n1-n2; }
        else                     { s = (const float2*)xx;  d = x_bf;  k = i-n0-n1-n2-n3; }
        float2 v = s[k];
        d[k] = h2m ? pack_h2(v.x, v.y)
                   : ((u32)to_bf16_(v.x) | ((u32)to_bf16_(v.y) << 16));
    }
}

// ---------------------------------------------------------------------------
// 128x128-tile bf16 MFMA GEMM: C[M,N] = A[M,K] @ W[N,K]^T (+bias).
// ---------------------------------------------------------------------------
#define LSTR 40
template<int HAS_BIAS>
__global__ void __launch_bounds__(256) gemm_mfma128(
    const u16* __restrict__ A, const u16* __restrict__ W,
    const float* __restrict__ bias,
    float* __restrict__ C, int M, int N, int K) {
    __shared__ __align__(16) u16 Asl[128*LSTR];
    __shared__ __align__(16) u16 Bsl[128*LSTR];
    int tid = threadIdx.x;
    int wave = tid >> 6, lane = tid & 63;
    int m0 = blockIdx.y*128, n0 = blockIdx.x*128;
    int m0w = (wave >> 1)*64, n0w = (wave & 1)*64;
    int fr = lane & 15, quad = lane >> 4;
    f32x4 acc[4][4];
#pragma unroll
    for (int mi = 0; mi < 4; ++mi)
#pragma unroll
        for (int ni = 0; ni < 4; ++ni) acc[mi][ni] = (f32x4){0.f,0.f,0.f,0.f};

    int srow = tid & 127;
    const u16* gp = (tid < 128) ? (A + (size_t)(m0+srow)*K) : (W + (size_t)(n0+srow)*K);
    u16* lp = (tid < 128) ? (Asl + srow*LSTR) : (Bsl + srow*LSTR);

    for (int k0 = 0; k0 < K; k0 += 32) {
        uint4 v0 = *(const uint4*)(gp + k0 + 0);
        uint4 v1 = *(const uint4*)(gp + k0 + 8);
        uint4 v2 = *(const uint4*)(gp + k0 + 16);
        uint4 v3 = *(const uint4*)(gp + k0 + 24);
        __syncthreads();
        *(uint4*)(lp + 0)  = v0;
        *(uint4*)(lp + 8)  = v1;
        *(uint4*)(lp + 16) = v2;
        *(uint4*)(lp + 24) = v3;
        __syncthreads();
        short8 af[4], bf[4];
#pragma unroll
        for (int mi = 0; mi < 4; ++mi)
            af[mi] = *(const short8*)&Asl[(m0w + mi*16 + fr)*LSTR + quad*8];
#pragma unroll
        for (int ni = 0; ni < 4; ++ni)
            bf[ni] = *(const short8*)&Bsl[(n0w + ni*16 + fr)*LSTR + quad*8];
#pragma unroll
        for (int mi = 0; mi < 4; ++mi)
#pragma unroll
            for (int ni = 0; ni < 4; ++ni)
                acc[mi][ni] = __builtin_amdgcn_mfma_f32_16x16x32_bf16(af[mi], bf[ni],
                                                                      acc[mi][ni], 0, 0, 0);
    }
#pragma unroll
    for (int ni = 0; ni < 4; ++ni) {
        int col = n0 + n0w + ni*16 + fr;
        float bb = HAS_BIAS ? bias[col] : 0.f;
#pragma unroll
        for (int mi = 0; mi < 4; ++mi) {
#pragma unroll
            for (int r = 0; r < 4; ++r) {
                int row = m0 + m0w + mi*16 + quad*4 + r;
                C[(size_t)row*N + col] = acc[mi][ni][r] + bb;
            }
        }
    }
}

// ---------------------------------------------------------------------------
// 64x64 bf16 MFMA GEMM (out_proj)
// ---------------------------------------------------------------------------
template<int HAS_BIAS>
__global__ void __launch_bounds__(256) gemm_mfma_nt(
    const u16* __restrict__ A, const u16* __restrict__ W,
    const float* __restrict__ bias,
    float* __restrict__ C, int M, int N, int K) {
    __shared__ __align__(16) u16 Asl[64*LSTR];
    __shared__ __align__(16) u16 Bsl[64*LSTR];
    int tid = threadIdx.x;
    int wave = tid >> 6, lane = tid & 63;
    int m0 = blockIdx.y*64, n0 = blockIdx.x*64;
    int mstrip = wave*16;
    int fr = lane & 15, quad = lane >> 4;
    f32x4 acc[4];
#pragma unroll
    for (int nt = 0; nt < 4; ++nt) acc[nt] = (f32x4){0.f,0.f,0.f,0.f};
    int srow = tid >> 2, sk = (tid & 3)*8;
    const u16* Ap = A + (size_t)(m0+srow)*K + sk;
    const u16* Wp = W + (size_t)(n0+srow)*K + sk;
    for (int k0 = 0; k0 < K; k0 += 32) {
        uint4 av = *(const uint4*)(Ap + k0);
        uint4 bv = *(const uint4*)(Wp + k0);
        __syncthreads();
        *(uint4*)&Asl[srow*LSTR + sk] = av;
        *(uint4*)&Bsl[srow*LSTR + sk] = bv;
        __syncthreads();
        short8 af = *(const short8*)&Asl[(mstrip+fr)*LSTR + quad*8];
#pragma unroll
        for (int nt = 0; nt < 4; ++nt) {
            short8 bf = *(const short8*)&Bsl[(nt*16+fr)*LSTR + quad*8];
            acc[nt] = __builtin_amdgcn_mfma_f32_16x16x32_bf16(af, bf, acc[nt], 0, 0, 0);
        }
    }
#pragma unroll
    for (int nt = 0; nt < 4; ++nt) {
        int col = n0 + nt*16 + fr;
        float bb = HAS_BIAS ? bias[col] : 0.f;
#pragma unroll
        for (int r = 0; r < 4; ++r) {
            int row = m0 + mstrip + quad*4 + r;
            C[(size_t)row*N + col] = acc[nt][r] + bb;
        }
    }
}

// ---------------------------------------------------------------------------
// Generic fp32 GEMM (precision-sensitive projections)
// ---------------------------------------------------------------------------
template<int ACT>
__global__ void __launch_bounds__(256) gemm_nt(
    const float* __restrict__ A, int lda,
    const float* __restrict__ W,
    const float* __restrict__ bias, float bias_scale,
    float* __restrict__ C, int M, int N, int K) {
    __shared__ __align__(16) float As[16*72];
    __shared__ __align__(16) float Ws[16*72];
    int tid = threadIdx.x;
    int tx = tid & 15, ty = tid >> 4;
    int m0 = blockIdx.y*64, n0 = blockIdx.x*64;
    float acc[4][4];
#pragma unroll
    for (int i = 0; i < 4; ++i)
#pragma unroll
        for (int j = 0; j < 4; ++j) acc[i][j] = 0.f;
    int kq = tid & 15;
    int mq = tid >> 4;
    for (int k0 = 0; k0 < K; k0 += 16) {
#pragma unroll
        for (int r = 0; r < 4; ++r) {
            int m = mq + r*16;
            As[kq*72 + m] = A[(size_t)(m0+m)*lda + k0 + kq];
            int n = n0 + m;
            Ws[kq*72 + m] = (n < N) ? W[(size_t)n*K + k0 + kq] : 0.f;
        }
        __syncthreads();
#pragma unroll
        for (int kk = 0; kk < 16; ++kk) {
            float4 a4 = *(const float4*)&As[kk*72 + ty*4];
            float4 b4 = *(const float4*)&Ws[kk*72 + tx*4];
            float av[4] = {a4.x, a4.y, a4.z, a4.w};
            float bv[4] = {b4.x, b4.y, b4.z, b4.w};
#pragma unroll
            for (int i = 0; i < 4; ++i)
#pragma unroll
                for (int j = 0; j < 4; ++j) acc[i][j] += av[i]*bv[j];
        }
        __syncthreads();
    }
#pragma unroll
    for (int i = 0; i < 4; ++i) {
        int m = m0 + ty*4 + i;
#pragma unroll
        for (int j = 0; j < 4; ++j) {
            int n = n0 + tx*4 + j;
            if (n < N) {
                float v = acc[i][j];
                if (bias) v += bias_scale*bias[n];
                if (ACT == 1) v = (v > 20.f) ? v : log1pf(__expf(v));
                C[(size_t)m*N + n] = v;
            }
        }
    }
}

// ---------------------------------------------------------------------------
// Causal depthwise conv (width 4) + SiLU. Dual-writes fp32 + bf16.
// ---------------------------------------------------------------------------
__global__ void conv_silu(const float* __restrict__ xz, const float* __restrict__ conv_w,
                          const float* __restrict__ conv_b, float* __restrict__ x_conv,
                          u16* __restrict__ x_conv_bf) {
    int idx = blockIdx.x*blockDim.x + threadIdx.x;
    int d = idx & (DINNER-1);
    int bt = idx >> 11;
    int t = bt & (LSEQ-1); int b = bt >> 9;
    float acc = conv_b[d];
#pragma unroll
    for (int k = 0; k < DCONV; ++k) {
        int tt = t - (DCONV-1) + k;
        if (tt >= 0) acc += xz[((size_t)(b*LSEQ+tt))*(2*DINNER) + d] * conv_w[d*DCONV + k];
    }
    float v = acc * sigmoidf_(acc);
    x_conv[idx] = v;
    x_conv_bf[idx] = to_bf16_(v);
}

// ---------------------------------------------------------------------------
// Persistent GRU scan v6 — direct per-wave tagged u32 publish.
// 256 blocks x 1024 threads, 2 chains (one per batch), 128 blocks each.
// Unit j's state = u32 (tag16 | fp16), published by its wave's lane 0
// IMMEDIATELY after the gate math (before any barrier) -> fast waves' values
// start cross-chip transit while slow waves still compute. Readers poll 2
// u32 per thread (concurrent), pack to fdot2 pair layout in LDS.
// WAR across parity buffers safe by induction (publish of S_{t+1} requires
// staging all of S_t, which requires every block fully staged S_{t-1}).
// Tags 0..512 fit 16 bits; memset(0) == S_0 (tag 0, fp16 0).
// ---------------------------------------------------------------------------
#define GRU_NBLK 256
#define GRU_THREADS 1024

__global__ void __launch_bounds__(GRU_THREADS, 1) gru_kernel(
    const u32* __restrict__ whh_h2, const float* __restrict__ gi,
    const float* __restrict__ bhh, u32* __restrict__ hT,
    float* __restrict__ h_gru) {
    __shared__ u32 h2[DINNER/2];    // 4 KB: fp16 pair per 2 units
    int blk = blockIdx.x;
    int tid = threadIdx.x;
    int w = tid >> 6, lane = tid & 63;
    int b = blk >> 7;
    int j0 = (blk & 127) << 4;
    int j = j0 + w;                 // unit this wave owns

    u32 wr[3][16];
#pragma unroll
    for (int g = 0; g < 3; ++g) {
        const u32* row = whh_h2 + ((size_t)(g*DINNER + j))*(DINNER/2);
#pragma unroll
        for (int i = 0; i < 16; ++i) wr[g][i] = row[lane + 64*i];
    }
    float b_r = 0.f, b_z = 0.f, b_n = 0.f, hp = 0.f;
    if (lane == 0) { b_r = bhh[j]; b_z = bhh[DINNER+j]; b_n = bhh[2*DINNER+j]; }

    u32* my = hT + (size_t)(b*2)*DINNER;   // chain buffers: [parity][unit]
    const float* gib = gi + (size_t)b*LSEQ*(3*DINNER);

    for (int t = 0; t < LSEQ; ++t) {
        int par = t & 1;
        // prefetch gi (in flight during the poll)
        float ir = 0.f, iz = 0.f, inn = 0.f;
        if (lane == 0) {
            const float* g0 = gib + (size_t)t*(3*DINNER);
            ir = g0[j]; iz = g0[DINNER+j]; inn = g0[2*DINNER+j];
        }
        // ---- poll + stage: 2 tagged u32 per thread (units 2tid, 2tid+1) ----
        {
            const u32* src = my + (size_t)par*DINNER;
            u32 v0 = __hip_atomic_load(&src[2*tid],   __ATOMIC_RELAXED,
                                       __HIP_MEMORY_SCOPE_AGENT);
            u32 v1 = __hip_atomic_load(&src[2*tid+1], __ATOMIC_RELAXED,
                                       __HIP_MEMORY_SCOPE_AGENT);
            while (((v0 >> 16) != (u32)t) | ((v1 >> 16) != (u32)t)) {
                __builtin_amdgcn_s_sleep(1);
                if ((v0 >> 16) != (u32)t)
                    v0 = __hip_atomic_load(&src[2*tid],   __ATOMIC_RELAXED,
                                           __HIP_MEMORY_SCOPE_AGENT);
                if ((v1 >> 16) != (u32)t)
                    v1 = __hip_atomic_load(&src[2*tid+1], __ATOMIC_RELAXED,
                                           __HIP_MEMORY_SCOPE_AGENT);
            }
            h2[tid] = (v0 & 0xFFFFu) | (v1 << 16);
        }
        __syncthreads();
        // ---- 3 dots of 2048 via v_dot2_f32_f16 ----
        float s0 = 0.f, s1 = 0.f, s2 = 0.f;
#pragma unroll
        for (int i = 0; i < 16; ++i) {
            h2_t hv = __builtin_bit_cast(h2_t, h2[lane + 64*i]);
            s0 = __builtin_amdgcn_fdot2(__builtin_bit_cast(h2_t, wr[0][i]), hv, s0, false);
            s1 = __builtin_amdgcn_fdot2(__builtin_bit_cast(h2_t, wr[1][i]), hv, s1, false);
            s2 = __builtin_amdgcn_fdot2(__builtin_bit_cast(h2_t, wr[2][i]), hv, s2, false);
        }
#pragma unroll
        for (int off = 32; off; off >>= 1) {
            s0 += __shfl_xor(s0, off, 64);
            s1 += __shfl_xor(s1, off, 64);
            s2 += __shfl_xor(s2, off, 64);
        }
        if (lane == 0) {
            float r  = sigmoidf_(ir + s0 + b_r);
            float uu = sigmoidf_(iz + s1 + b_z);
            float nn = tanhf(inn + r*(s2 + b_n));
            float hn = (1.f-uu)*nn + uu*hp;
            hp = hn;                                   // exact fp32 self-path
            // publish IMMEDIATELY (no barrier before cross-chip transit)
            u32 pk = ((u32)(t+1) << 16) | (u32)to_h16_(hn);
            __hip_atomic_store(&my[(size_t)(1-par)*DINNER + j], pk,
                               __ATOMIC_RELAXED, __HIP_MEMORY_SCOPE_AGENT);
            h_gru[((size_t)(b*LSEQ + t))*DINNER + j] = hn;
        }
        __syncthreads();   // WAR: all waves done reading h2 before next staging
    }
}

// ---------------------------------------------------------------------------
__global__ void __launch_bounds__(64) content_kernel(
    const float* __restrict__ xc, const float* __restrict__ Wc,
    float* __restrict__ content) {
    int bt = blockIdx.x;
    int lane = threadIdx.x;
    const float4* xr = (const float4*)(xc + (size_t)bt*DINNER);
    float4 xv[8];
#pragma unroll
    for (int r = 0; r < 8; ++r) xv[r] = xr[lane + 64*r];
#pragma unroll
    for (int g = 0; g < EVENTD; ++g) {
        const float4* wrow = (const float4*)(Wc + (size_t)g*DINNER);
        float s = 0.f;
#pragma unroll
        for (int r = 0; r < 8; ++r) {
            float4 w4 = wrow[lane + 64*r];
            s += xv[r].x*w4.x + xv[r].y*w4.y + xv[r].z*w4.z + xv[r].w*w4.w;
        }
#pragma unroll
        for (int off = 32; off; off >>= 1) s += __shfl_down(s, off, 64);
        if (lane == 0) content[(size_t)bt*EVENTD + g] = s;
    }
}

__global__ void scaling_kernel(const float* __restrict__ h_gru, const float* __restrict__ WT_w,
                               const float* __restrict__ WT_b, const float* __restrict__ delta,
                               float* __restrict__ scaling, float* __restrict__ stg,
                               float* __restrict__ out_last) {
    __shared__ float red[4];
    int bt = blockIdx.x;
    int tid = threadIdx.x;
    const float* h = h_gru + (size_t)bt*DINNER;
    float p = 0.f;
    for (int k = tid; k < DINNER; k += 256) p += h[k]*WT_w[k];
#pragma unroll
    for (int off = 32; off; off >>= 1) p += __shfl_down(p, off, 64);
    if ((tid & 63) == 0) red[tid >> 6] = p;
    __syncthreads();
    if (tid == 0) {
        float v = red[0]+red[1]+red[2]+red[3] + WT_b[0];
        v = fminf(fmaxf(v, -10.f), 10.f);
        float sp = log1pf(__expf(v));
        sp = fminf(fmaxf(sp, 0.1f), 10.f);
        scaling[bt] = sp;
        stg[bt] = delta[bt]*sp;
        if ((bt & (LSEQ-1)) == LSEQ-1) out_last[bt >> 9] = sp;
    }
}

__global__ void intervals_kernel(const float* __restrict__ stg, float* __restrict__ intervals) {
    int idx = blockIdx.x*256 + threadIdx.x;
    if (idx < BT) {
        float v = stg[idx];
        if (idx & (LSEQ-1)) v -= stg[idx-1];
        intervals[idx] = v;
    }
}

__global__ void bdual_kernel(const float* __restrict__ content, const float* __restrict__ stg,
                             const float* __restrict__ Wtau_w, const float* __restrict__ B0,
                             float* __restrict__ B_dual) {
    int idx = blockIdx.x*256 + threadIdx.x;
    int n = idx & 15, bt = idx >> 4;
    float v = (n < EVENTD) ? content[bt*EVENTD + n] : stg[bt]*Wtau_w[n - EVENTD];
    B_dual[idx] = B0[n]*sigmoidf_(v);
}

// ---------------------------------------------------------------------------
// Chunked parallel selective scan (3 passes, exact per-step recurrence).
// ---------------------------------------------------------------------------
__global__ void __launch_bounds__(256) scan_pass1(
    const float* __restrict__ base_dt, const float* __restrict__ intervals,
    const float* __restrict__ B_dual, const float* __restrict__ x_conv,
    const float* __restrict__ A_log,
    float* __restrict__ Aprod, float* __restrict__ hend) {
    int idx = blockIdx.x*256 + threadIdx.x;
    int d = idx & (DINNER-1);
    int c = (idx >> 11) & (NCH-1);
    int b = idx >> 16;
    float Arow[DSTATE];
#pragma unroll
    for (int n = 0; n < DSTATE; ++n) Arow[n] = -__expf(A_log[d*DSTATE + n]);
    float h[DSTATE], P[DSTATE];
#pragma unroll
    for (int n = 0; n < DSTATE; ++n) { h[n] = 0.f; P[n] = 1.f; }
    for (int tt = 0; tt < CL; ++tt) {
        int t = c*CL + tt;
        size_t row = (size_t)b*LSEQ + t;
        float dt = intervals[row]*base_dt[row*DINNER + d];
        dt = fminf(fmaxf(dt, 1e-6f), 10.f);
        float xc = x_conv[row*DINNER + d];
        const float* Bd = B_dual + row*DSTATE;
#pragma unroll
        for (int n = 0; n < DSTATE; ++n) {
            float e = fminf(fmaxf(dt*Arow[n], -20.f), 20.f);
            float da = __expf(e);
            h[n] = da*h[n] + (dt*Bd[n])*xc;
            P[n] *= da;
        }
    }
    size_t base = ((size_t)(b*NCH + c)*DSTATE)*DINNER + d;
#pragma unroll
    for (int n = 0; n < DSTATE; ++n) {
        Aprod[base + (size_t)n*DINNER] = P[n];
        hend[base + (size_t)n*DINNER] = h[n];
    }
}

__global__ void __launch_bounds__(256) scan_pass2(
    const float* __restrict__ Aprod, const float* __restrict__ hend,
    float* __restrict__ hinit) {
    int idx = blockIdx.x*256 + threadIdx.x;
    int d = idx & (DINNER-1);
    int n = (idx >> 11) & (DSTATE-1);
    int b = idx >> 15;
    float carry = 0.f;
    for (int c = 0; c < NCH; ++c) {
        size_t o = ((size_t)(b*NCH + c)*DSTATE + n)*DINNER + d;
        hinit[o] = carry;
        carry = Aprod[o]*carry + hend[o];
    }
}

__global__ void __launch_bounds__(256) scan_pass3(
    const float* __restrict__ base_dt, const float* __restrict__ intervals,
    const float* __restrict__ B_dual, const float* __restrict__ x_dbl,
    const float* __restrict__ x_conv, const float* __restrict__ xz,
    const float* __restrict__ A_log, const float* __restrict__ D_param,
    const float* __restrict__ hinit, u16* __restrict__ y_bf) {
    int idx = blockIdx.x*256 + threadIdx.x;
    int d = idx & (DINNER-1);
    int c = (idx >> 11) & (NCH-1);
    int b = idx >> 16;
    float Arow[DSTATE];
#pragma unroll
    for (int n = 0; n < DSTATE; ++n) Arow[n] = -__expf(A_log[d*DSTATE + n]);
    float Dd = D_param[d];
    float h[DSTATE];
    size_t hib = ((size_t)(b*NCH + c)*DSTATE)*DINNER + d;
#pragma unroll
    for (int n = 0; n < DSTATE; ++n) h[n] = hinit[hib + (size_t)n*DINNER];
    for (int tt = 0; tt < CL; ++tt) {
        int t = c*CL + tt;
        size_t row = (size_t)b*LSEQ + t;
        float dt = intervals[row]*base_dt[row*DINNER + d];
        dt = fminf(fmaxf(dt, 1e-6f), 10.f);
        float xc = x_conv[row*DINNER + d];
        const float* Bd = B_dual + row*DSTATE;
        const float* Cc = x_dbl + row*96 + DTRANK + DSTATE;
        float y = 0.f;
#pragma unroll
        for (int n = 0; n < DSTATE; ++n) {
            float e = fminf(fmaxf(dt*Arow[n], -20.f), 20.f);
            float da = __expf(e);
            h[n] = da*h[n] + (dt*Bd[n])*xc;
            y += h[n]*Cc[n];
        }
        float z = xz[row*(2*DINNER) + DINNER + d];
        y_bf[row*DINNER + d] = to_bf16_((y + xc*Dd) * (z*sigmoidf_(z)));
    }
}

// ---------------------------------------------------------------------------
extern "C" void kernel_launch(void* const* d_in, const int* in_sizes, int n_in,
                              void* d_out, int out_size, void* d_ws, size_t ws_size,
                              hipStream_t stream) {
    const float* x         = (const float*)d_in[0];
    const float* delta     = (const float*)d_in[1];
    const float* in_proj_w = (const float*)d_in[2];
    const float* conv_w    = (const float*)d_in[3];
    const float* conv_b    = (const float*)d_in[4];
    const float* gru_wih   = (const float*)d_in[5];
    const float* gru_whh   = (const float*)d_in[6];
    const float* gru_bih   = (const float*)d_in[7];
    const float* gru_bhh   = (const float*)d_in[8];
    const float* WT_w      = (const float*)d_in[9];
    const float* WT_b      = (const float*)d_in[10];
    const float* Wc_w      = (const float*)d_in[11];
    const float* Wtau_w    = (const float*)d_in[12];
    const float* B0        = (const float*)d_in[13];
    const float* xproj_w   = (const float*)d_in[14];
    const float* dtproj_w  = (const float*)d_in[15];
    const float* dtproj_b  = (const float*)d_in[16];
    const float* A_log     = (const float*)d_in[17];
    const float* D_param   = (const float*)d_in[18];
    const float* outproj_w = (const float*)d_in[19];
    float* out = (float*)d_out;

    float* ws = (float*)d_ws;
    size_t off = 0;
    float* xz        = ws + off; off += (size_t)BT*2*DINNER;
    float* x_conv    = ws + off; off += (size_t)BT*DINNER;
    float* gi        = ws + off; off += (size_t)BT*3*DINNER;   // dead after GRU ->
    float* Aprod     = gi;                                      //   chunk scratch
    float* hend      = gi + (size_t)BT*DINNER;
    float* hinit     = gi + (size_t)2*BT*DINNER;
    u32*   whh_h2    = (u32*)(ws + off); off += (size_t)3*DINNER*DINNER/2;
    float* h_gru     = ws + off; off += (size_t)BT*DINNER;
    float* base_dt   = ws + off; off += (size_t)BT*DINNER;
    float* x_dbl     = ws + off; off += (size_t)BT*96;
    float* content   = ws + off; off += (size_t)BT*16;
    float* B_dual    = ws + off; off += (size_t)BT*16;
    float* scaling   = ws + off; off += BT;
    float* stg       = ws + off; off += BT;
    float* intervals = ws + off; off += BT;
    u32*   hT        = (u32*)(ws + off); off += 2*2*DINNER/1;   // 2 chains x 2 par x 2048 u32
    u16*   x_bf      = (u16*)(ws + off); off += (size_t)BT*DMODEL/2;
    u16*   inprojw_bf= (u16*)(ws + off); off += (size_t)2*DINNER*DMODEL/2;
    u16*   wih_bf    = (u16*)(ws + off); off += (size_t)3*DINNER*DINNER/2;
    u16*   outw_bf   = (u16*)(ws + off); off += (size_t)DMODEL*DINNER/2;
    u16*   xconv_bf  = (u16*)(ws + off); off += (size_t)BT*DINNER/2;
    u16*   y_bf      = (u16*)(ws + off); off += (size_t)BT*DINNER/2;

    // init tagged-h buffers (tag=0 == S_0 ready, h=0)
    hipMemsetAsync(hT, 0, (size_t)2*2*DINNER*sizeof(u32), stream);

    // fused weight/activation conversions
    convert_all<<<8192, 256, 0, stream>>>(gru_whh, whh_h2,
                                          in_proj_w, (u32*)inprojw_bf,
                                          gru_wih, (u32*)wih_bf,
                                          outproj_w, (u32*)outw_bf,
                                          x, (u32*)x_bf);

    // xz = x @ in_proj_w.T            (1024 x 4096, K=1024)  [MFMA 128-tile]
    gemm_mfma128<0><<<dim3(32,8), 256, 0, stream>>>(x_bf, inprojw_bf, nullptr,
                                                    xz, BT, 2*DINNER, DMODEL);
    conv_silu<<<(BT*DINNER)/256, 256, 0, stream>>>(xz, conv_w, conv_b, x_conv, xconv_bf);

    // gi = x_conv @ gru_wih.T + bih   (1024 x 6144, K=2048)  [MFMA 128-tile]
    gemm_mfma128<1><<<dim3(48,8), 256, 0, stream>>>(xconv_bf, wih_bf, gru_bih,
                                                    gi, BT, 3*DINNER, DINNER);

    gru_kernel<<<GRU_NBLK, GRU_THREADS, 0, stream>>>(whh_h2, gi, gru_bhh, hT, h_gru);

    scaling_kernel<<<BT, 256, 0, stream>>>(h_gru, WT_w, WT_b, delta, scaling, stg,
                                           out + (size_t)BT*DMODEL);
    intervals_kernel<<<4, 256, 0, stream>>>(stg, intervals);

    // x_dbl = x_conv @ xproj_w.T      (1024 x 96, K=2048)  [fp32, precision path]
    gemm_nt<0><<<dim3(2,16), 256, 0, stream>>>(x_conv, DINNER, xproj_w, nullptr, 0.f,
                                               x_dbl, BT, 96, DINNER);
    // base_dt = softplus(dt_low @ dtproj_w.T + 2*dtproj_b)  [fp32]
    gemm_nt<1><<<dim3(32,16), 256, 0, stream>>>(x_dbl, 96, dtproj_w, dtproj_b, 2.f,
                                                base_dt, BT, DINNER, DTRANK);
    // content = x_conv @ Wc_w.T       (1024 x 10, K=2048)
    content_kernel<<<BT, 64, 0, stream>>>(x_conv, Wc_w, content);
    bdual_kernel<<<(BT*16)/256, 256, 0, stream>>>(content, stg, Wtau_w, B0, B_dual);

    // chunked parallel selective scan (+ fused y epilogue)
    scan_pass1<<<(BATCH*NCH*DINNER)/256, 256, 0, stream>>>(base_dt, intervals, B_dual,
                                                           x_conv, A_log, Aprod, hend);
    scan_pass2<<<(BATCH*DSTATE*DINNER)/256, 256, 0, stream>>>(Aprod, hend, hinit);
    scan_pass3<<<(BATCH*NCH*DINNER)/256, 256, 0, stream>>>(base_dt, intervals, B_dual,
                                                           x_dbl, x_conv, xz, A_log,
                                                           D_param, hinit, y_bf);

    // out = y @ outproj_w.T           (1024 x 1024, K=2048)  [MFMA 64-tile]
    gemm_mfma_nt<0><<<dim3(16,16), 256, 0, stream>>>(y_bf, outw_bf, nullptr,
                                                     out, BT, DMODEL, DINNER);
}

// Round 8
// 1988.601 us; speedup vs baseline: 1.5578x; 1.5578x over previous
//
#include <hip/hip_runtime.h>
#include <hip/hip_bf16.h>

// Sizes (fixed for this problem)
#define BATCH 2
#define LSEQ 512
#define DMODEL 1024
#define DINNER 2048
#define DSTATE 16
#define DTRANK 64
#define DCONV 4
#define EVENTD 10
#define TIMED 6
#define BT (BATCH*LSEQ)   // 1024
#define NCH 32            // scan chunks
#define CL  16            // steps per chunk (NCH*CL == LSEQ)

typedef unsigned int u32;
typedef unsigned short u16;
typedef unsigned long long u64;
typedef __attribute__((ext_vector_type(8))) short short8;
typedef __attribute__((ext_vector_type(4))) float f32x4;
typedef _Float16 h2_t __attribute__((ext_vector_type(2)));

__device__ __forceinline__ float sigmoidf_(float x) { return 1.f/(1.f+__expf(-x)); }
__device__ __forceinline__ u16 to_bf16_(float f) {
    u32 u = __float_as_uint(f);
    return (u16)((u + 0x7FFFu + ((u >> 16) & 1u)) >> 16);
}
__device__ __forceinline__ u32 pack_h2(float a, float b) {
    _Float16 ha = (_Float16)a, hb = (_Float16)b;
    u16 ua, ub;
    __builtin_memcpy(&ua, &ha, 2);
    __builtin_memcpy(&ub, &hb, 2);
    return (u32)ua | ((u32)ub << 16);
}

// ---------------------------------------------------------------------------
// Fused weight/activation conversion (pair-granular, one kernel).
// whh -> fp16 pairs; ipw/wih/opw/x -> bf16 pairs.
// ---------------------------------------------------------------------------
__global__ void convert_all(const float* __restrict__ whh, u32* __restrict__ whh_h2,
                            const float* __restrict__ ipw, u32* __restrict__ ipw_bf,
                            const float* __restrict__ wih, u32* __restrict__ wih_bf,
                            const float* __restrict__ opw, u32* __restrict__ opw_bf,
                            const float* __restrict__ xx,  u32* __restrict__ x_bf) {
    const int n0 = 3*DINNER*DINNER/2;        // fp16 pairs
    const int n1 = 2*DINNER*DMODEL/2;
    const int n2 = 3*DINNER*DINNER/2;
    const int n3 = DMODEL*DINNER/2;
    const int n4 = BT*DMODEL/2;
    int total = n0+n1+n2+n3+n4;
    for (int i = blockIdx.x*blockDim.x + threadIdx.x; i < total; i += gridDim.x*blockDim.x) {
        const float2* s; u32* d; int k; bool h2m = false;
        if (i < n0)              { s = (const float2*)whh; d = whh_h2; k = i; h2m = true; }
        else if (i < n0+n1)      { s = (const float2*)ipw; d = ipw_bf; k = i-n0; }
        else if (i < n0+n1+n2)   { s = (const float2*)wih; d = wih_bf; k = i-n0-n1; }
        else if (i < n0+n1+n2+n3){ s = (const float2*)opw; d = opw_bf; k = i-n0-n1-n2; }
        else                     { s = (const float2*)xx;  d = x_bf;  k = i-n0-n1-n2-n3; }
        float2 v = s[k];
        d[k] = h2m ? pack_h2(v.x, v.y)
                   : ((u32)to_bf16_(v.x) | ((u32)to_bf16_(v.y) << 16));
    }
}

// ---------------------------------------------------------------------------
// 128x128-tile bf16 MFMA GEMM: C[M,N] = A[M,K] @ W[N,K]^T (+bias).
// ---------------------------------------------------------------------------
#define LSTR 40
template<int HAS_BIAS>
__global__ void __launch_bounds__(256) gemm_mfma128(
    const u16* __restrict__ A, const u16* __restrict__ W,
    const float* __restrict__ bias,
    float* __restrict__ C, int M, int N, int K) {
    __shared__ __align__(16) u16 Asl[128*LSTR];
    __shared__ __align__(16) u16 Bsl[128*LSTR];
    int tid = threadIdx.x;
    int wave = tid >> 6, lane = tid & 63;
    int m0 = blockIdx.y*128, n0 = blockIdx.x*128;
    int m0w = (wave >> 1)*64, n0w = (wave & 1)*64;
    int fr = lane & 15, quad = lane >> 4;
    f32x4 acc[4][4];
#pragma unroll
    for (int mi = 0; mi < 4; ++mi)
#pragma unroll
        for (int ni = 0; ni < 4; ++ni) acc[mi][ni] = (f32x4){0.f,0.f,0.f,0.f};

    int srow = tid & 127;
    const u16* gp = (tid < 128) ? (A + (size_t)(m0+srow)*K) : (W + (size_t)(n0+srow)*K);
    u16* lp = (tid < 128) ? (Asl + srow*LSTR) : (Bsl + srow*LSTR);

    for (int k0 = 0; k0 < K; k0 += 32) {
        uint4 v0 = *(const uint4*)(gp + k0 + 0);
        uint4 v1 = *(const uint4*)(gp + k0 + 8);
        uint4 v2 = *(const uint4*)(gp + k0 + 16);
        uint4 v3 = *(const uint4*)(gp + k0 + 24);
        __syncthreads();
        *(uint4*)(lp + 0)  = v0;
        *(uint4*)(lp + 8)  = v1;
        *(uint4*)(lp + 16) = v2;
        *(uint4*)(lp + 24) = v3;
        __syncthreads();
        short8 af[4], bf[4];
#pragma unroll
        for (int mi = 0; mi < 4; ++mi)
            af[mi] = *(const short8*)&Asl[(m0w + mi*16 + fr)*LSTR + quad*8];
#pragma unroll
        for (int ni = 0; ni < 4; ++ni)
            bf[ni] = *(const short8*)&Bsl[(n0w + ni*16 + fr)*LSTR + quad*8];
#pragma unroll
        for (int mi = 0; mi < 4; ++mi)
#pragma unroll
            for (int ni = 0; ni < 4; ++ni)
                acc[mi][ni] = __builtin_amdgcn_mfma_f32_16x16x32_bf16(af[mi], bf[ni],
                                                                      acc[mi][ni], 0, 0, 0);
    }
#pragma unroll
    for (int ni = 0; ni < 4; ++ni) {
        int col = n0 + n0w + ni*16 + fr;
        float bb = HAS_BIAS ? bias[col] : 0.f;
#pragma unroll
        for (int mi = 0; mi < 4; ++mi) {
#pragma unroll
            for (int r = 0; r < 4; ++r) {
                int row = m0 + m0w + mi*16 + quad*4 + r;
                C[(size_t)row*N + col] = acc[mi][ni][r] + bb;
            }
        }
    }
}

// ---------------------------------------------------------------------------
// 64x64 bf16 MFMA GEMM (out_proj)
// ---------------------------------------------------------------------------
template<int HAS_BIAS>
__global__ void __launch_bounds__(256) gemm_mfma_nt(
    const u16* __restrict__ A, const u16* __restrict__ W,
    const float* __restrict__ bias,
    float* __restrict__ C, int M, int N, int K) {
    __shared__ __align__(16) u16 Asl[64*LSTR];
    __shared__ __align__(16) u16 Bsl[64*LSTR];
    int tid = threadIdx.x;
    int wave = tid >> 6, lane = tid & 63;
    int m0 = blockIdx.y*64, n0 = blockIdx.x*64;
    int mstrip = wave*16;
    int fr = lane & 15, quad = lane >> 4;
    f32x4 acc[4];
#pragma unroll
    for (int nt = 0; nt < 4; ++nt) acc[nt] = (f32x4){0.f,0.f,0.f,0.f};
    int srow = tid >> 2, sk = (tid & 3)*8;
    const u16* Ap = A + (size_t)(m0+srow)*K + sk;
    const u16* Wp = W + (size_t)(n0+srow)*K + sk;
    for (int k0 = 0; k0 < K; k0 += 32) {
        uint4 av = *(const uint4*)(Ap + k0);
        uint4 bv = *(const uint4*)(Wp + k0);
        __syncthreads();
        *(uint4*)&Asl[srow*LSTR + sk] = av;
        *(uint4*)&Bsl[srow*LSTR + sk] = bv;
        __syncthreads();
        short8 af = *(const short8*)&Asl[(mstrip+fr)*LSTR + quad*8];
#pragma unroll
        for (int nt = 0; nt < 4; ++nt) {
            short8 bf = *(const short8*)&Bsl[(nt*16+fr)*LSTR + quad*8];
            acc[nt] = __builtin_amdgcn_mfma_f32_16x16x32_bf16(af, bf, acc[nt], 0, 0, 0);
        }
    }
#pragma unroll
    for (int nt = 0; nt < 4; ++nt) {
        int col = n0 + nt*16 + fr;
        float bb = HAS_BIAS ? bias[col] : 0.f;
#pragma unroll
        for (int r = 0; r < 4; ++r) {
            int row = m0 + mstrip + quad*4 + r;
            C[(size_t)row*N + col] = acc[nt][r] + bb;
        }
    }
}

// ---------------------------------------------------------------------------
// Generic fp32 GEMM (precision-sensitive projections)
// ---------------------------------------------------------------------------
template<int ACT>
__global__ void __launch_bounds__(256) gemm_nt(
    const float* __restrict__ A, int lda,
    const float* __restrict__ W,
    const float* __restrict__ bias, float bias_scale,
    float* __restrict__ C, int M, int N, int K) {
    __shared__ __align__(16) float As[16*72];
    __shared__ __align__(16) float Ws[16*72];
    int tid = threadIdx.x;
    int tx = tid & 15, ty = tid >> 4;
    int m0 = blockIdx.y*64, n0 = blockIdx.x*64;
    float acc[4][4];
#pragma unroll
    for (int i = 0; i < 4; ++i)
#pragma unroll
        for (int j = 0; j < 4; ++j) acc[i][j] = 0.f;
    int kq = tid & 15;
    int mq = tid >> 4;
    for (int k0 = 0; k0 < K; k0 += 16) {
#pragma unroll
        for (int r = 0; r < 4; ++r) {
            int m = mq + r*16;
            As[kq*72 + m] = A[(size_t)(m0+m)*lda + k0 + kq];
            int n = n0 + m;
            Ws[kq*72 + m] = (n < N) ? W[(size_t)n*K + k0 + kq] : 0.f;
        }
        __syncthreads();
#pragma unroll
        for (int kk = 0; kk < 16; ++kk) {
            float4 a4 = *(const float4*)&As[kk*72 + ty*4];
            float4 b4 = *(const float4*)&Ws[kk*72 + tx*4];
            float av[4] = {a4.x, a4.y, a4.z, a4.w};
            float bv[4] = {b4.x, b4.y, b4.z, b4.w};
#pragma unroll
            for (int i = 0; i < 4; ++i)
#pragma unroll
                for (int j = 0; j < 4; ++j) acc[i][j] += av[i]*bv[j];
        }
        __syncthreads();
    }
#pragma unroll
    for (int i = 0; i < 4; ++i) {
        int m = m0 + ty*4 + i;
#pragma unroll
        for (int j = 0; j < 4; ++j) {
            int n = n0 + tx*4 + j;
            if (n < N) {
                float v = acc[i][j];
                if (bias) v += bias_scale*bias[n];
                if (ACT == 1) v = (v > 20.f) ? v : log1pf(__expf(v));
                C[(size_t)m*N + n] = v;
            }
        }
    }
}

// ---------------------------------------------------------------------------
// Causal depthwise conv (width 4) + SiLU. Dual-writes fp32 + bf16.
// ---------------------------------------------------------------------------
__global__ void conv_silu(const float* __restrict__ xz, const float* __restrict__ conv_w,
                          const float* __restrict__ conv_b, float* __restrict__ x_conv,
                          u16* __restrict__ x_conv_bf) {
    int idx = blockIdx.x*blockDim.x + threadIdx.x;
    int d = idx & (DINNER-1);
    int bt = idx >> 11;
    int t = bt & (LSEQ-1); int b = bt >> 9;
    float acc = conv_b[d];
#pragma unroll
    for (int k = 0; k < DCONV; ++k) {
        int tt = t - (DCONV-1) + k;
        if (tt >= 0) acc += xz[((size_t)(b*LSEQ+tt))*(2*DINNER) + d] * conv_w[d*DCONV + k];
    }
    float v = acc * sigmoidf_(acc);
    x_conv[idx] = v;
    x_conv_bf[idx] = to_bf16_(v);
}

// ---------------------------------------------------------------------------
// Persistent GRU scan v5 (REVERTED to the verified 1.37 ms exchange).
// 256 blocks x 1024 threads, 2 chains (one per batch). Wave owns 1 unit
// (3 gate dots of 2048 via v_dot2_f32_f16, weights in 48 VGPRs fp16 pairs).
// Exchange: 1024 u64/chain, each (tag32 | 2xfp16). ONE tagged load/thread.
// Publish: LDS pack, then ONE wave issues 8 coalesced u64 stores — coalesced
// publish width beats publish earliness (R7 regression: 16 scattered 4B
// stores -> +57 MB WRITE_SIZE, 1.8x slower).
// ---------------------------------------------------------------------------
#define GRU_NBLK 256
#define GRU_THREADS 1024

__global__ void __launch_bounds__(GRU_THREADS, 1) gru_kernel(
    const u32* __restrict__ whh_h2, const float* __restrict__ gi,
    const float* __restrict__ bhh, u64* __restrict__ hT,
    float* __restrict__ h_gru) {
    __shared__ u32 h2[DINNER/2];
    __shared__ float pub[16];
    int blk = blockIdx.x;
    int tid = threadIdx.x;
    int w = tid >> 6, lane = tid & 63;
    int b = blk >> 7;
    int j0 = (blk & 127) << 4;
    int j = j0 + w;

    u32 wr[3][16];
#pragma unroll
    for (int g = 0; g < 3; ++g) {
        const u32* row = whh_h2 + ((size_t)(g*DINNER + j))*(DINNER/2);
#pragma unroll
        for (int i = 0; i < 16; ++i) wr[g][i] = row[lane + 64*i];
    }
    float b_r = 0.f, b_z = 0.f, b_n = 0.f, hp = 0.f;
    if (lane == 0) { b_r = bhh[j]; b_z = bhh[DINNER+j]; b_n = bhh[2*DINNER+j]; }

    u64* my = hT + (size_t)(b*2)*(DINNER/2);
    const float* gib = gi + (size_t)b*LSEQ*(3*DINNER);

    for (int t = 0; t < LSEQ; ++t) {
        int par = t & 1;
        float ir = 0.f, iz = 0.f, inn = 0.f;
        if (lane == 0) {
            const float* g0 = gib + (size_t)t*(3*DINNER);
            ir = g0[j]; iz = g0[DINNER+j]; inn = g0[2*DINNER+j];
        }
        {
            const u64* src = my + par*(DINNER/2);
            u64 v = __hip_atomic_load(&src[tid], __ATOMIC_RELAXED,
                                      __HIP_MEMORY_SCOPE_AGENT);
            while ((u32)(v >> 32) != (u32)t) {
                __builtin_amdgcn_s_sleep(1);
                v = __hip_atomic_load(&src[tid], __ATOMIC_RELAXED,
                                      __HIP_MEMORY_SCOPE_AGENT);
            }
            h2[tid] = (u32)v;
        }
        __syncthreads();
        float s0 = 0.f, s1 = 0.f, s2 = 0.f;
#pragma unroll
        for (int i = 0; i < 16; ++i) {
            h2_t hv = __builtin_bit_cast(h2_t, h2[lane + 64*i]);
            s0 = __builtin_amdgcn_fdot2(__builtin_bit_cast(h2_t, wr[0][i]), hv, s0, false);
            s1 = __builtin_amdgcn_fdot2(__builtin_bit_cast(h2_t, wr[1][i]), hv, s1, false);
            s2 = __builtin_amdgcn_fdot2(__builtin_bit_cast(h2_t, wr[2][i]), hv, s2, false);
        }
#pragma unroll
        for (int off = 32; off; off >>= 1) {
            s0 += __shfl_xor(s0, off, 64);
            s1 += __shfl_xor(s1, off, 64);
            s2 += __shfl_xor(s2, off, 64);
        }
        if (lane == 0) {
            float r  = sigmoidf_(ir + s0 + b_r);
            float uu = sigmoidf_(iz + s1 + b_z);
            float nn = tanhf(inn + r*(s2 + b_n));
            float hn = (1.f-uu)*nn + uu*hp;
            hp = hn;
            h_gru[((size_t)(b*LSEQ + t))*DINNER + j] = hn;
            pub[w] = hn;
        }
        __syncthreads();
        if (tid < 8) {
            u32 pr = pack_h2(pub[2*tid], pub[2*tid+1]);
            __hip_atomic_store(&my[(1-par)*(DINNER/2) + (j0 >> 1) + tid],
                               ((u64)(u32)(t+1) << 32) | (u64)pr,
                               __ATOMIC_RELAXED, __HIP_MEMORY_SCOPE_AGENT);
        }
    }
}

// ---------------------------------------------------------------------------
__global__ void __launch_bounds__(64) content_kernel(
    const float* __restrict__ xc, const float* __restrict__ Wc,
    float* __restrict__ content) {
    int bt = blockIdx.x;
    int lane = threadIdx.x;
    const float4* xr = (const float4*)(xc + (size_t)bt*DINNER);
    float4 xv[8];
#pragma unroll
    for (int r = 0; r < 8; ++r) xv[r] = xr[lane + 64*r];
#pragma unroll
    for (int g = 0; g < EVENTD; ++g) {
        const float4* wrow = (const float4*)(Wc + (size_t)g*DINNER);
        float s = 0.f;
#pragma unroll
        for (int r = 0; r < 8; ++r) {
            float4 w4 = wrow[lane + 64*r];
            s += xv[r].x*w4.x + xv[r].y*w4.y + xv[r].z*w4.z + xv[r].w*w4.w;
        }
#pragma unroll
        for (int off = 32; off; off >>= 1) s += __shfl_down(s, off, 64);
        if (lane == 0) content[(size_t)bt*EVENTD + g] = s;
    }
}

__global__ void scaling_kernel(const float* __restrict__ h_gru, const float* __restrict__ WT_w,
                               const float* __restrict__ WT_b, const float* __restrict__ delta,
                               float* __restrict__ scaling, float* __restrict__ stg,
                               float* __restrict__ out_last) {
    __shared__ float red[4];
    int bt = blockIdx.x;
    int tid = threadIdx.x;
    const float* h = h_gru + (size_t)bt*DINNER;
    float p = 0.f;
    for (int k = tid; k < DINNER; k += 256) p += h[k]*WT_w[k];
#pragma unroll
    for (int off = 32; off; off >>= 1) p += __shfl_down(p, off, 64);
    if ((tid & 63) == 0) red[tid >> 6] = p;
    __syncthreads();
    if (tid == 0) {
        float v = red[0]+red[1]+red[2]+red[3] + WT_b[0];
        v = fminf(fmaxf(v, -10.f), 10.f);
        float sp = log1pf(__expf(v));
        sp = fminf(fmaxf(sp, 0.1f), 10.f);
        scaling[bt] = sp;
        stg[bt] = delta[bt]*sp;
        if ((bt & (LSEQ-1)) == LSEQ-1) out_last[bt >> 9] = sp;
    }
}

// intervals + B_dual fused (both elementwise after scaling/content)
__global__ void intervals_bdual_kernel(const float* __restrict__ stg,
                                       const float* __restrict__ content,
                                       const float* __restrict__ Wtau_w,
                                       const float* __restrict__ B0,
                                       float* __restrict__ intervals,
                                       float* __restrict__ B_dual) {
    int idx = blockIdx.x*256 + threadIdx.x;      // BT*16
    int n = idx & 15, bt = idx >> 4;
    if (n == 0) {
        float v = stg[bt];
        if (bt & (LSEQ-1)) v -= stg[bt-1];
        intervals[bt] = v;
    }
    float v = (n < EVENTD) ? content[bt*EVENTD + n] : stg[bt]*Wtau_w[n - EVENTD];
    B_dual[idx] = B0[n]*sigmoidf_(v);
}

// ---------------------------------------------------------------------------
// Chunked parallel selective scan (3 passes, exact per-step recurrence).
// ---------------------------------------------------------------------------
__global__ void __launch_bounds__(256) scan_pass1(
    const float* __restrict__ base_dt, const float* __restrict__ intervals,
    const float* __restrict__ B_dual, const float* __restrict__ x_conv,
    const float* __restrict__ A_log,
    float* __restrict__ Aprod, float* __restrict__ hend) {
    int idx = blockIdx.x*256 + threadIdx.x;
    int d = idx & (DINNER-1);
    int c = (idx >> 11) & (NCH-1);
    int b = idx >> 16;
    float Arow[DSTATE];
#pragma unroll
    for (int n = 0; n < DSTATE; ++n) Arow[n] = -__expf(A_log[d*DSTATE + n]);
    float h[DSTATE], P[DSTATE];
#pragma unroll
    for (int n = 0; n < DSTATE; ++n) { h[n] = 0.f; P[n] = 1.f; }
    for (int tt = 0; tt < CL; ++tt) {
        int t = c*CL + tt;
        size_t row = (size_t)b*LSEQ + t;
        float dt = intervals[row]*base_dt[row*DINNER + d];
        dt = fminf(fmaxf(dt, 1e-6f), 10.f);
        float xc = x_conv[row*DINNER + d];
        const float* Bd = B_dual + row*DSTATE;
#pragma unroll
        for (int n = 0; n < DSTATE; ++n) {
            float e = fminf(fmaxf(dt*Arow[n], -20.f), 20.f);
            float da = __expf(e);
            h[n] = da*h[n] + (dt*Bd[n])*xc;
            P[n] *= da;
        }
    }
    size_t base = ((size_t)(b*NCH + c)*DSTATE)*DINNER + d;
#pragma unroll
    for (int n = 0; n < DSTATE; ++n) {
        Aprod[base + (size_t)n*DINNER] = P[n];
        hend[base + (size_t)n*DINNER] = h[n];
    }
}

__global__ void __launch_bounds__(256) scan_pass2(
    const float* __restrict__ Aprod, const float* __restrict__ hend,
    float* __restrict__ hinit) {
    int idx = blockIdx.x*256 + threadIdx.x;
    int d = idx & (DINNER-1);
    int n = (idx >> 11) & (DSTATE-1);
    int b = idx >> 15;
    float carry = 0.f;
    for (int c = 0; c < NCH; ++c) {
        size_t o = ((size_t)(b*NCH + c)*DSTATE + n)*DINNER + d;
        hinit[o] = carry;
        carry = Aprod[o]*carry + hend[o];
    }
}

__global__ void __launch_bounds__(256) scan_pass3(
    const float* __restrict__ base_dt, const float* __restrict__ intervals,
    const float* __restrict__ B_dual, const float* __restrict__ x_dbl,
    const float* __restrict__ x_conv, const float* __restrict__ xz,
    const float* __restrict__ A_log, const float* __restrict__ D_param,
    const float* __restrict__ hinit, u16* __restrict__ y_bf) {
    int idx = blockIdx.x*256 + threadIdx.x;
    int d = idx & (DINNER-1);
    int c = (idx >> 11) & (NCH-1);
    int b = idx >> 16;
    float Arow[DSTATE];
#pragma unroll
    for (int n = 0; n < DSTATE; ++n) Arow[n] = -__expf(A_log[d*DSTATE + n]);
    float Dd = D_param[d];
    float h[DSTATE];
    size_t hib = ((size_t)(b*NCH + c)*DSTATE)*DINNER + d;
#pragma unroll
    for (int n = 0; n < DSTATE; ++n) h[n] = hinit[hib + (size_t)n*DINNER];
    for (int tt = 0; tt < CL; ++tt) {
        int t = c*CL + tt;
        size_t row = (size_t)b*LSEQ + t;
        float dt = intervals[row]*base_dt[row*DINNER + d];
        dt = fminf(fmaxf(dt, 1e-6f), 10.f);
        float xc = x_conv[row*DINNER + d];
        const float* Bd = B_dual + row*DSTATE;
        const float* Cc = x_dbl + row*96 + DTRANK + DSTATE;
        float y = 0.f;
#pragma unroll
        for (int n = 0; n < DSTATE; ++n) {
            float e = fminf(fmaxf(dt*Arow[n], -20.f), 20.f);
            float da = __expf(e);
            h[n] = da*h[n] + (dt*Bd[n])*xc;
            y += h[n]*Cc[n];
        }
        float z = xz[row*(2*DINNER) + DINNER + d];
        y_bf[row*DINNER + d] = to_bf16_((y + xc*Dd) * (z*sigmoidf_(z)));
    }
}

// ---------------------------------------------------------------------------
extern "C" void kernel_launch(void* const* d_in, const int* in_sizes, int n_in,
                              void* d_out, int out_size, void* d_ws, size_t ws_size,
                              hipStream_t stream) {
    const float* x         = (const float*)d_in[0];
    const float* delta     = (const float*)d_in[1];
    const float* in_proj_w = (const float*)d_in[2];
    const float* conv_w    = (const float*)d_in[3];
    const float* conv_b    = (const float*)d_in[4];
    const float* gru_wih   = (const float*)d_in[5];
    const float* gru_whh   = (const float*)d_in[6];
    const float* gru_bih   = (const float*)d_in[7];
    const float* gru_bhh   = (const float*)d_in[8];
    const float* WT_w      = (const float*)d_in[9];
    const float* WT_b      = (const float*)d_in[10];
    const float* Wc_w      = (const float*)d_in[11];
    const float* Wtau_w    = (const float*)d_in[12];
    const float* B0        = (const float*)d_in[13];
    const float* xproj_w   = (const float*)d_in[14];
    const float* dtproj_w  = (const float*)d_in[15];
    const float* dtproj_b  = (const float*)d_in[16];
    const float* A_log     = (const float*)d_in[17];
    const float* D_param   = (const float*)d_in[18];
    const float* outproj_w = (const float*)d_in[19];
    float* out = (float*)d_out;

    float* ws = (float*)d_ws;
    size_t off = 0;
    float* xz        = ws + off; off += (size_t)BT*2*DINNER;
    float* x_conv    = ws + off; off += (size_t)BT*DINNER;
    float* gi        = ws + off; off += (size_t)BT*3*DINNER;   // dead after GRU ->
    float* Aprod     = gi;                                      //   chunk scratch
    float* hend      = gi + (size_t)BT*DINNER;
    float* hinit     = gi + (size_t)2*BT*DINNER;
    u32*   whh_h2    = (u32*)(ws + off); off += (size_t)3*DINNER*DINNER/2;
    float* h_gru     = ws + off; off += (size_t)BT*DINNER;
    float* base_dt   = ws + off; off += (size_t)BT*DINNER;
    float* x_dbl     = ws + off; off += (size_t)BT*96;
    float* content   = ws + off; off += (size_t)BT*16;
    float* B_dual    = ws + off; off += (size_t)BT*16;
    float* scaling   = ws + off; off += BT;
    float* stg       = ws + off; off += BT;
    float* intervals = ws + off; off += BT;
    u64*   hT        = (u64*)(ws + off); off += 2*(2*2*DINNER);  // 2 chains x 2 par x 1024 u64
    u16*   x_bf      = (u16*)(ws + off); off += (size_t)BT*DMODEL/2;
    u16*   inprojw_bf= (u16*)(ws + off); off += (size_t)2*DINNER*DMODEL/2;
    u16*   wih_bf    = (u16*)(ws + off); off += (size_t)3*DINNER*DINNER/2;
    u16*   outw_bf   = (u16*)(ws + off); off += (size_t)DMODEL*DINNER/2;
    u16*   xconv_bf  = (u16*)(ws + off); off += (size_t)BT*DINNER/2;
    u16*   y_bf      = (u16*)(ws + off); off += (size_t)BT*DINNER/2;

    // init tagged-h buffers (tag=0 == S_0 ready, h=0)
    hipMemsetAsync(hT, 0, (size_t)2*2*(DINNER/2)*sizeof(u64), stream);

    // fused weight/activation conversions
    convert_all<<<8192, 256, 0, stream>>>(gru_whh, whh_h2,
                                          in_proj_w, (u32*)inprojw_bf,
                                          gru_wih, (u32*)wih_bf,
                                          outproj_w, (u32*)outw_bf,
                                          x, (u32*)x_bf);

    // xz = x @ in_proj_w.T            (1024 x 4096, K=1024)  [MFMA 128-tile]
    gemm_mfma128<0><<<dim3(32,8), 256, 0, stream>>>(x_bf, inprojw_bf, nullptr,
                                                    xz, BT, 2*DINNER, DMODEL);
    conv_silu<<<(BT*DINNER)/256, 256, 0, stream>>>(xz, conv_w, conv_b, x_conv, xconv_bf);

    // gi = x_conv @ gru_wih.T + bih   (1024 x 6144, K=2048)  [MFMA 128-tile]
    gemm_mfma128<1><<<dim3(48,8), 256, 0, stream>>>(xconv_bf, wih_bf, gru_bih,
                                                    gi, BT, 3*DINNER, DINNER);

    gru_kernel<<<GRU_NBLK, GRU_THREADS, 0, stream>>>(whh_h2, gi, gru_bhh, hT, h_gru);

    scaling_kernel<<<BT, 256, 0, stream>>>(h_gru, WT_w, WT_b, delta, scaling, stg,
                                           out + (size_t)BT*DMODEL);

    // x_dbl = x_conv @ xproj_w.T      (1024 x 96, K=2048)  [fp32, precision path]
    gemm_nt<0><<<dim3(2,16), 256, 0, stream>>>(x_conv, DINNER, xproj_w, nullptr, 0.f,
                                               x_dbl, BT, 96, DINNER);
    // base_dt = softplus(dt_low @ dtproj_w.T + 2*dtproj_b)  [fp32]
    gemm_nt<1><<<dim3(32,16), 256, 0, stream>>>(x_dbl, 96, dtproj_w, dtproj_b, 2.f,
                                                base_dt, BT, DINNER, DTRANK);
    // content = x_conv @ Wc_w.T       (1024 x 10, K=2048)
    content_kernel<<<BT, 64, 0, stream>>>(x_conv, Wc_w, content);
    intervals_bdual_kernel<<<(BT*16)/256, 256, 0, stream>>>(stg, content, Wtau_w, B0,
                                                            intervals, B_dual);

    // chunked parallel selective scan (+ fused y epilogue)
    scan_pass1<<<(BATCH*NCH*DINNER)/256, 256, 0, stream>>>(base_dt, intervals, B_dual,
                                                           x_conv, A_log, Aprod, hend);
    scan_pass2<<<(BATCH*DSTATE*DINNER)/256, 256, 0, stream>>>(Aprod, hend, hinit);
    scan_pass3<<<(BATCH*NCH*DINNER)/256, 256, 0, stream>>>(base_dt, intervals, B_dual,
                                                           x_dbl, x_conv, xz, A_log,
                                                           D_param, hinit, y_bf);

    // out = y @ outproj_w.T           (1024 x 1024, K=2048)  [MFMA 64-tile]
    gemm_mfma_nt<0><<<dim3(16,16), 256, 0, stream>>>(y_bf, outw_bf, nullptr,
                                                     out, BT, DMODEL, DINNER);
}